// Round 8
// baseline (186.284 us; speedup 1.0000x reference)
//
#include <hip/hip_runtime.h>

#define B_    32
#define C_    512
#define HW2_  1024
#define NW    77
#define NP    80     // n padded to 80 (5 x 16 MFMA rows)
#define NPT   96     // n pitch for P (3 K-steps of 32), cols >=77: P=0
#define WD    256

typedef unsigned int   uint32;
typedef unsigned short u16;
typedef __attribute__((ext_vector_type(8))) short bf16x8;  // MFMA A/B frag (4 VGPR)
typedef __attribute__((ext_vector_type(4))) float f32x4;   // MFMA C/D frag

#define MFMA(a, b, c) __builtin_amdgcn_mfma_f32_16x16x32_bf16(a, b, c, 0, 0, 0)
#define SWALL() __builtin_amdgcn_sched_barrier(0)

// raw async global load + counted waits (compiler never emits counted vmcnt)
#define GLD4(dst, ptr) asm volatile("global_load_dwordx4 %0, %1, off" \
                                    : "=v"(dst) : "v"(ptr))
#define VMWAIT(n) asm volatile("s_waitcnt vmcnt(" #n ")" ::: "memory")

// workspace element counts (bf16x8 = 16 B units)
// we planes:  [b][q=16][n=80][kloc=64]  -> idx = ((b*16+q)*80+n)*8 + kloc/8
// weT planes: [b][kout=1024][n=96]      -> idx = (b*1024+kout)*12 + n/8
#define WE_ELN   ((size_t)B_ * 16 * NP * 8)     // 327680
#define WET_ELN  ((size_t)B_ * HW2_ * 12)       // 393216

// fp32 -> (hi, lo) bf16 split. hi = truncation, residual exact, lo = RNE.
__device__ __forceinline__ void split1(float x, u16 &h, u16 &l) {
    uint32 u = __float_as_uint(x);
    h = (u16)(u >> 16);
    float r = x - __uint_as_float(u & 0xffff0000u);   // exact
    uint32 v = __float_as_uint(r);
    l = (u16)((v + 0x7fffu + ((v >> 16) & 1u)) >> 16);
}

__device__ __forceinline__ void split8(float4 a, float4 b, bf16x8 &h, bf16x8 &l) {
    float v[8] = {a.x, a.y, a.z, a.w, b.x, b.y, b.z, b.w};
    #pragma unroll
    for (int i = 0; i < 8; ++i) {
        u16 hh, ll; split1(v[i], hh, ll);
        h[i] = (short)hh; l[i] = (short)ll;
    }
}

// ---------------------------------------------------------------------------
// Kernel 1: we = word_emb @ W_fc^T + b_fc via MFMA (4-term split fused).
// UNCHANGED from round 7 (single-variable round; attn carries the change).
// ---------------------------------------------------------------------------
__global__ __launch_bounds__(512, 4) void we_gemm(
    const float* __restrict__ word_emb, const float* __restrict__ W_fc,
    const float* __restrict__ b_fc,
    bf16x8* __restrict__ we_hi, bf16x8* __restrict__ we_lo,
    bf16x8* __restrict__ weT_hi, bf16x8* __restrict__ weT_lo)
{
    __shared__ __align__(16) uint32 HL[NP][68];   // (hi<<16)|lo, 21.8 KB

    const int id = blockIdx.x;
    const int b  = (id & 7) + 8 * (id >> 7);      // XCD = id%8 = b%8
    const int q  = (id >> 3) & 15;
    const int kb = q * 64;
    const int t  = threadIdx.x;
    const int h  = t >> 6;                        // wave 0..7
    const int w  = h & 3, nh = h >> 2;
    const int lane = t & 63, lr = lane & 15, lg = lane >> 4;
    const int kout = kb + 16 * w + lr;
    const int m0 = nh ? 3 : 0;                    // n-tile range per wave
    const int mc = nh ? 2 : 3;

    const float* wrow = W_fc + kout * WD;
    bf16x8 bh[8], bl[8];
    #pragma unroll
    for (int c = 0; c < 2; ++c) {
        float4 wx[4], wy[4];
        #pragma unroll
        for (int i = 0; i < 4; ++i) {
            const int dk = (c * 4 + i) * 32 + 8 * lg;
            wx[i] = *(const float4*)(wrow + dk);
            wy[i] = *(const float4*)(wrow + dk + 4);
        }
        SWALL();
        #pragma unroll
        for (int i = 0; i < 4; ++i) split8(wx[i], wy[i], bh[c * 4 + i], bl[c * 4 + i]);
    }

    f32x4 acc[3];
    #pragma unroll
    for (int mm = 0; mm < 3; ++mm) acc[mm] = (f32x4)0.0f;

    const float* emb = word_emb + b * NW * WD;

    #pragma unroll
    for (int ks = 0; ks < 8; ++ks) {
        const int dk = ks * 32 + 8 * lg;
        bf16x8 ah[3], al[3];
        #pragma unroll
        for (int mm = 0; mm < 3; ++mm) {
            if (mm < mc) {
                const int n = 16 * (m0 + mm) + lr;
                float4 x = make_float4(0.f, 0.f, 0.f, 0.f), y = x;
                if (n < NW) {
                    const float* p = emb + n * WD + dk;
                    x = *(const float4*)p; y = *(const float4*)(p + 4);
                }
                split8(x, y, ah[mm], al[mm]);
            }
        }
        #pragma unroll
        for (int mm = 0; mm < 3; ++mm) {
            if (mm < mc) {
                acc[mm] = MFMA(ah[mm], bh[ks], acc[mm]);
                acc[mm] = MFMA(ah[mm], bl[ks], acc[mm]);
                acc[mm] = MFMA(al[mm], bh[ks], acc[mm]);
                acc[mm] = MFMA(al[mm], bl[ks], acc[mm]);
            }
        }
    }

    const float bias = b_fc[kout];
    #pragma unroll
    for (int mm = 0; mm < 3; ++mm) {
        if (mm < mc) {
            #pragma unroll
            for (int r = 0; r < 4; ++r) {
                u16 hh, ll; split1(acc[mm][r] + bias, hh, ll);
                HL[16 * (m0 + mm) + 4 * lg + r][16 * w + lr] = ((uint32)hh << 16) | ll;
            }
        }
    }
    __syncthreads();

    for (int u = t; u < 640; u += 512) {
        const int n = u >> 3, c8 = (u & 7) * 8;
        uint4 p0 = *(const uint4*)&HL[n][c8];
        uint4 p1 = *(const uint4*)&HL[n][c8 + 4];
        const uint32 pw[8] = {p0.x, p0.y, p0.z, p0.w, p1.x, p1.y, p1.z, p1.w};
        bf16x8 hv, lv;
        #pragma unroll
        for (int i = 0; i < 8; ++i) {
            hv[i] = (short)(pw[i] >> 16);
            lv[i] = (short)(pw[i] & 0xffffu);
        }
        const int o = ((b * 16 + q) * NP + n) * 8 + (u & 7);
        we_hi[o] = hv; we_lo[o] = lv;
    }
    #pragma unroll
    for (int v0 = 0; v0 < 1536; v0 += 512) {
        const int v = v0 + t;
        const int sel = v >= 768;
        const int r2  = sel ? v - 768 : v;
        const int row = r2 / 12, g = r2 % 12;
        bf16x8 val;
        #pragma unroll
        for (int i = 0; i < 8; ++i) {
            const int n = g * 8 + i;
            const uint32 p = (n < NP) ? HL[n][row] : 0u;
            val[i] = (short)(sel ? (p & 0xffffu) : (p >> 16));
        }
        (sel ? weT_lo : weT_hi)[(b * HW2_ + kb + row) * 12 + g] = val;
    }
}

// ---------------------------------------------------------------------------
// Kernel 2: fused scores^T -> softmax -> out via MFMA (3-term split).
// 512 thr = 8 waves, 32 c-rows/block, grid 512, XCD-swizzled (as r7).
// NEW: phase 1 = 2-deep 3-slot inline-asm load pipeline with counted vmcnt
// (14 loads/set: 4 feat + 10 we); phase 3 = 1-deep 2-slot ring, vmcnt(8)
// conservatively counting the 2 interleaved stores. sched_barrier(0) after
// every wait (asm-load results are "ready" to the scheduler before the wait).
// ---------------------------------------------------------------------------
__global__ __launch_bounds__(512, 2) void attn_mfma(
    const float* __restrict__ feat,
    const bf16x8* __restrict__ we_hi, const bf16x8* __restrict__ we_lo,
    const bf16x8* __restrict__ weT_hi, const bf16x8* __restrict__ weT_lo,
    float* __restrict__ out)
{
    __shared__ __align__(16) float S[8][16][84];  // partial scores (43 KB)
    __shared__ __align__(16) u16   Ph[32][NPT];   // P hi (6 KB)
    __shared__ __align__(16) u16   Pl[32][NPT];   // P lo (6 KB)

    const int id  = blockIdx.x;
    const int b   = (id & 7) + 8 * (id >> 7);     // batch -> XCD id&7 (=b%8)
    const int c0  = ((id >> 3) & 15) * 32;        // block's 32 c rows

    const int t    = threadIdx.x;
    const int h    = t >> 6;                      // wave = K-eighth, 0..7
    const int lane = t & 63, lr = lane & 15, lg = lane >> 4;

    const float* frow0 = feat + (size_t)(b * C_ + c0 + lr) * HW2_;
    const float* frow1 = frow0 + 16 * HW2_;

    // ---- Phase 1: 2-deep 3-slot pipeline, 14 asm loads per K-set ----------
    float4 F[3][4];                                // 48 VGPR
    bf16x8 WH[3][5], WL[3][5];                     // 120 VGPR

#define P1_ISS(sl, ksv) do {                                        \
        const int kk_ = h * 128 + (ksv) * 32 + 8 * lg;              \
        GLD4(F[sl][0], frow0 + kk_);                                \
        GLD4(F[sl][1], frow0 + kk_ + 4);                            \
        GLD4(F[sl][2], frow1 + kk_);                                \
        GLD4(F[sl][3], frow1 + kk_ + 4);                            \
        const int qb_  = (b * 16 + 2 * h + ((ksv) >> 1)) * NP;      \
        const int sub_ = ((ksv) & 1) * 4 + lg;                      \
        _Pragma("unroll")                                           \
        for (int m_ = 0; m_ < 5; ++m_) {                            \
            GLD4(WH[sl][m_], we_hi + (qb_ + 16 * m_ + lr) * 8 + sub_); \
            GLD4(WL[sl][m_], we_lo + (qb_ + 16 * m_ + lr) * 8 + sub_); \
        } } while (0)

    f32x4 acc[2][5];
    #pragma unroll
    for (int s = 0; s < 2; ++s)
        #pragma unroll
        for (int m = 0; m < 5; ++m) acc[s][m] = (f32x4)0.0f;

#define P1_COMP(sl) do {                                            \
        bf16x8 fh0, fl0, fh1, fl1;                                  \
        split8(F[sl][0], F[sl][1], fh0, fl0);                       \
        split8(F[sl][2], F[sl][3], fh1, fl1);                       \
        _Pragma("unroll")                                           \
        for (int m_ = 0; m_ < 5; ++m_) {                            \
            acc[0][m_] = MFMA(WH[sl][m_], fh0, acc[0][m_]);         \
            acc[0][m_] = MFMA(WH[sl][m_], fl0, acc[0][m_]);         \
            acc[0][m_] = MFMA(WL[sl][m_], fh0, acc[0][m_]);         \
            acc[1][m_] = MFMA(WH[sl][m_], fh1, acc[1][m_]);         \
            acc[1][m_] = MFMA(WH[sl][m_], fl1, acc[1][m_]);         \
            acc[1][m_] = MFMA(WL[sl][m_], fh1, acc[1][m_]);         \
        } } while (0)

    P1_ISS(0, 0);
    P1_ISS(1, 1);
    P1_ISS(2, 2); VMWAIT(28); SWALL(); P1_COMP(0);
    P1_ISS(0, 3); VMWAIT(28); SWALL(); P1_COMP(1);
    VMWAIT(14);   SWALL();             P1_COMP(2);
    VMWAIT(0);    SWALL();             P1_COMP(0);   // set 3 lives in slot 0
#undef P1_ISS
#undef P1_COMP

    // ---- merge (8 partials) + softmax, one 16-row strip at a time ---------
    #pragma unroll
    for (int s = 0; s < 2; ++s) {
        #pragma unroll
        for (int m = 0; m < 5; ++m)
            #pragma unroll
            for (int r = 0; r < 4; ++r)
                S[h][lr][16 * m + 4 * lg + r] = acc[s][m][r];
        __syncthreads();
        {
            const int srow = 2 * h + (lane >> 5), col0 = lane & 31;
            float v3[3];
            float mx = -3.0e38f;
            #pragma unroll
            for (int j = 0; j < 3; ++j) {
                const int n = col0 + 32 * j;
                float sv = S[0][srow][n] + S[1][srow][n] + S[2][srow][n] + S[3][srow][n]
                         + S[4][srow][n] + S[5][srow][n] + S[6][srow][n] + S[7][srow][n];
                if (n < NW) mx = fmaxf(mx, sv);
                v3[j] = sv;
            }
            mx = fmaxf(mx, __shfl_xor(mx, 1));
            mx = fmaxf(mx, __shfl_xor(mx, 2));
            mx = fmaxf(mx, __shfl_xor(mx, 4));
            mx = fmaxf(mx, __shfl_xor(mx, 8));
            mx = fmaxf(mx, __shfl_xor(mx, 16));
            float sum = 0.f;
            #pragma unroll
            for (int j = 0; j < 3; ++j) {
                const int n = col0 + 32 * j;
                const float e = (n < NW) ? __expf(v3[j] - mx) : 0.f;
                v3[j] = e; sum += e;
            }
            sum += __shfl_xor(sum, 1);
            sum += __shfl_xor(sum, 2);
            sum += __shfl_xor(sum, 4);
            sum += __shfl_xor(sum, 8);
            sum += __shfl_xor(sum, 16);
            const float inv = 1.0f / sum;
            #pragma unroll
            for (int j = 0; j < 3; ++j) {
                const int n = col0 + 32 * j;
                u16 ph, pl; split1(v3[j] * inv, ph, pl);
                Ph[16 * s + srow][n] = ph; Pl[16 * s + srow][n] = pl;
            }
        }
        __syncthreads();
    }

    // ---- Phase 3: 1-deep 2-slot asm ring on weT; wave h owns kout-eighth --
    bf16x8 pbh[2][3], pbl[2][3];
    #pragma unroll
    for (int s = 0; s < 2; ++s)
        #pragma unroll
        for (int ksn = 0; ksn < 3; ++ksn) {
            pbh[s][ksn] = *(const bf16x8*)&Ph[16 * s + lr][32 * ksn + 8 * lg];
            pbl[s][ksn] = *(const bf16x8*)&Pl[16 * s + lr][32 * ksn + 8 * lg];
        }
    const bf16x8* th = weT_hi + (size_t)b * HW2_ * 12;
    const bf16x8* tl = weT_lo + (size_t)b * HW2_ * 12;
    float* orow0 = out + (size_t)(b * C_ + c0 + lr) * HW2_;
    float* orow1 = orow0 + 16 * HW2_;

    bf16x8 wa[2][3], wb[2][3];
#define P3_ISS(sl, ttv) do {                                        \
        const int row_ = h * 128 + (ttv) * 16 + lr;                 \
        _Pragma("unroll")                                           \
        for (int k_ = 0; k_ < 3; ++k_) {                            \
            GLD4(wa[sl][k_], th + row_ * 12 + 4 * k_ + lg);         \
            GLD4(wb[sl][k_], tl + row_ * 12 + 4 * k_ + lg);         \
        } } while (0)

#define P3_COMP(sl, ttv) do {                                       \
        f32x4 o0 = (f32x4)0.0f, o1 = (f32x4)0.0f;                   \
        _Pragma("unroll")                                           \
        for (int ksn = 0; ksn < 3; ++ksn) {                         \
            o0 = MFMA(wa[sl][ksn], pbh[0][ksn], o0);                \
            o0 = MFMA(wa[sl][ksn], pbl[0][ksn], o0);                \
            o0 = MFMA(wb[sl][ksn], pbh[0][ksn], o0);                \
            o1 = MFMA(wa[sl][ksn], pbh[1][ksn], o1);                \
            o1 = MFMA(wa[sl][ksn], pbl[1][ksn], o1);                \
            o1 = MFMA(wb[sl][ksn], pbh[1][ksn], o1);                \
        }                                                           \
        const int col_ = h * 128 + (ttv) * 16 + 4 * lg;             \
        *(float4*)(orow0 + col_) = make_float4(o0[0], o0[1], o0[2], o0[3]); \
        *(float4*)(orow1 + col_) = make_float4(o1[0], o1[1], o1[2], o1[3]); \
        } while (0)

    P3_ISS(0, 0);
    P3_ISS(1, 1); VMWAIT(6); SWALL(); P3_COMP(0, 0);
    P3_ISS(0, 2); VMWAIT(8); SWALL(); P3_COMP(1, 1);
    P3_ISS(1, 3); VMWAIT(8); SWALL(); P3_COMP(0, 2);
    P3_ISS(0, 4); VMWAIT(8); SWALL(); P3_COMP(1, 3);
    P3_ISS(1, 5); VMWAIT(8); SWALL(); P3_COMP(0, 4);
    P3_ISS(0, 6); VMWAIT(8); SWALL(); P3_COMP(1, 5);
    P3_ISS(1, 7); VMWAIT(8); SWALL(); P3_COMP(0, 6);
    VMWAIT(2);    SWALL();            P3_COMP(1, 7);
#undef P3_ISS
#undef P3_COMP
}

// ---------------------------------------------------------------------------
extern "C" void kernel_launch(void* const* d_in, const int* in_sizes, int n_in,
                              void* d_out, int out_size, void* d_ws, size_t ws_size,
                              hipStream_t stream) {
    (void)in_sizes; (void)n_in; (void)out_size; (void)ws_size;
    const float* feat     = (const float*)d_in[0];
    const float* word_emb = (const float*)d_in[1];
    const float* W_fc     = (const float*)d_in[2];
    const float* b_fc     = (const float*)d_in[3];

    bf16x8* we_hi  = (bf16x8*)d_ws;
    bf16x8* we_lo  = we_hi  + WE_ELN;
    bf16x8* weT_hi = we_lo  + WE_ELN;
    bf16x8* weT_lo = weT_hi + WET_ELN;

    we_gemm<<<512, 512, 0, stream>>>(word_emb, W_fc, b_fc, we_hi, we_lo, weT_hi, weT_lo);
    attn_mfma<<<512, 512, 0, stream>>>(feat, we_hi, we_lo, weT_hi, weT_lo, (float*)d_out);
}

// Round 10
// 182.008 us; speedup vs baseline: 1.0235x; 1.0235x over previous
//
#include <hip/hip_runtime.h>

#define B_    32
#define C_    512
#define HW2_  1024
#define NW    77
#define NP    80     // n padded to 80 (5 x 16 MFMA rows)
#define NPT   96     // n pitch for P (3 K-steps of 32), cols >=77: P=0
#define WD    256

typedef unsigned int   uint32;
typedef unsigned short u16;
typedef __attribute__((ext_vector_type(8))) short bf16x8;  // MFMA A/B frag (4 VGPR)
typedef __attribute__((ext_vector_type(4))) float f32x4;   // MFMA C/D frag / NT vec

#define MFMA(a, b, c) __builtin_amdgcn_mfma_f32_16x16x32_bf16(a, b, c, 0, 0, 0)
#define SWALL() __builtin_amdgcn_sched_barrier(0)

// non-temporal 16B accessors (ext-vector type: HIP float4 is rejected)
#define NTLOAD(p)     __builtin_nontemporal_load((const f32x4*)(p))
#define NTSTORE(v, p) __builtin_nontemporal_store((v), (f32x4*)(p))

// workspace element counts (bf16x8 = 16 B units)
// we planes:  [b][q=16][n=80][kloc=64]  -> idx = ((b*16+q)*80+n)*8 + kloc/8
// weT planes: [b][kout=1024][n=96]      -> idx = (b*1024+kout)*12 + n/8
#define WE_ELN   ((size_t)B_ * 16 * NP * 8)     // 327680
#define WET_ELN  ((size_t)B_ * HW2_ * 12)       // 393216

// fp32 -> (hi, lo) bf16 split. hi = truncation, residual exact, lo = RNE.
__device__ __forceinline__ void split1(float x, u16 &h, u16 &l) {
    uint32 u = __float_as_uint(x);
    h = (u16)(u >> 16);
    float r = x - __uint_as_float(u & 0xffff0000u);   // exact
    uint32 v = __float_as_uint(r);
    l = (u16)((v + 0x7fffu + ((v >> 16) & 1u)) >> 16);
}

__device__ __forceinline__ void split8(float4 a, float4 b, bf16x8 &h, bf16x8 &l) {
    float v[8] = {a.x, a.y, a.z, a.w, b.x, b.y, b.z, b.w};
    #pragma unroll
    for (int i = 0; i < 8; ++i) {
        u16 hh, ll; split1(v[i], hh, ll);
        h[i] = (short)hh; l[i] = (short)ll;
    }
}

__device__ __forceinline__ void split8v(f32x4 a, f32x4 b, bf16x8 &h, bf16x8 &l) {
    float v[8] = {a[0], a[1], a[2], a[3], b[0], b[1], b[2], b[3]};
    #pragma unroll
    for (int i = 0; i < 8; ++i) {
        u16 hh, ll; split1(v[i], hh, ll);
        h[i] = (short)hh; l[i] = (short)ll;
    }
}

// ---------------------------------------------------------------------------
// Kernel 1: we = word_emb @ W_fc^T + b_fc via MFMA (4-term split fused).
// UNCHANGED from round 7 (attn carries this round's single variable).
// ---------------------------------------------------------------------------
__global__ __launch_bounds__(512, 4) void we_gemm(
    const float* __restrict__ word_emb, const float* __restrict__ W_fc,
    const float* __restrict__ b_fc,
    bf16x8* __restrict__ we_hi, bf16x8* __restrict__ we_lo,
    bf16x8* __restrict__ weT_hi, bf16x8* __restrict__ weT_lo)
{
    __shared__ __align__(16) uint32 HL[NP][68];   // (hi<<16)|lo, 21.8 KB

    const int id = blockIdx.x;
    const int b  = (id & 7) + 8 * (id >> 7);      // XCD = id%8 = b%8
    const int q  = (id >> 3) & 15;
    const int kb = q * 64;
    const int t  = threadIdx.x;
    const int h  = t >> 6;                        // wave 0..7
    const int w  = h & 3, nh = h >> 2;
    const int lane = t & 63, lr = lane & 15, lg = lane >> 4;
    const int kout = kb + 16 * w + lr;
    const int m0 = nh ? 3 : 0;                    // n-tile range per wave
    const int mc = nh ? 2 : 3;

    const float* wrow = W_fc + kout * WD;
    bf16x8 bh[8], bl[8];
    #pragma unroll
    for (int c = 0; c < 2; ++c) {
        float4 wx[4], wy[4];
        #pragma unroll
        for (int i = 0; i < 4; ++i) {
            const int dk = (c * 4 + i) * 32 + 8 * lg;
            wx[i] = *(const float4*)(wrow + dk);
            wy[i] = *(const float4*)(wrow + dk + 4);
        }
        SWALL();
        #pragma unroll
        for (int i = 0; i < 4; ++i) split8(wx[i], wy[i], bh[c * 4 + i], bl[c * 4 + i]);
    }

    f32x4 acc[3];
    #pragma unroll
    for (int mm = 0; mm < 3; ++mm) acc[mm] = (f32x4)0.0f;

    const float* emb = word_emb + b * NW * WD;

    #pragma unroll
    for (int ks = 0; ks < 8; ++ks) {
        const int dk = ks * 32 + 8 * lg;
        bf16x8 ah[3], al[3];
        #pragma unroll
        for (int mm = 0; mm < 3; ++mm) {
            if (mm < mc) {
                const int n = 16 * (m0 + mm) + lr;
                float4 x = make_float4(0.f, 0.f, 0.f, 0.f), y = x;
                if (n < NW) {
                    const float* p = emb + n * WD + dk;
                    x = *(const float4*)p; y = *(const float4*)(p + 4);
                }
                split8(x, y, ah[mm], al[mm]);
            }
        }
        #pragma unroll
        for (int mm = 0; mm < 3; ++mm) {
            if (mm < mc) {
                acc[mm] = MFMA(ah[mm], bh[ks], acc[mm]);
                acc[mm] = MFMA(ah[mm], bl[ks], acc[mm]);
                acc[mm] = MFMA(al[mm], bh[ks], acc[mm]);
                acc[mm] = MFMA(al[mm], bl[ks], acc[mm]);
            }
        }
    }

    const float bias = b_fc[kout];
    #pragma unroll
    for (int mm = 0; mm < 3; ++mm) {
        if (mm < mc) {
            #pragma unroll
            for (int r = 0; r < 4; ++r) {
                u16 hh, ll; split1(acc[mm][r] + bias, hh, ll);
                HL[16 * (m0 + mm) + 4 * lg + r][16 * w + lr] = ((uint32)hh << 16) | ll;
            }
        }
    }
    __syncthreads();

    for (int u = t; u < 640; u += 512) {
        const int n = u >> 3, c8 = (u & 7) * 8;
        uint4 p0 = *(const uint4*)&HL[n][c8];
        uint4 p1 = *(const uint4*)&HL[n][c8 + 4];
        const uint32 pw[8] = {p0.x, p0.y, p0.z, p0.w, p1.x, p1.y, p1.z, p1.w};
        bf16x8 hv, lv;
        #pragma unroll
        for (int i = 0; i < 8; ++i) {
            hv[i] = (short)(pw[i] >> 16);
            lv[i] = (short)(pw[i] & 0xffffu);
        }
        const int o = ((b * 16 + q) * NP + n) * 8 + (u & 7);
        we_hi[o] = hv; we_lo[o] = lv;
    }
    #pragma unroll
    for (int v0 = 0; v0 < 1536; v0 += 512) {
        const int v = v0 + t;
        const int sel = v >= 768;
        const int r2  = sel ? v - 768 : v;
        const int row = r2 / 12, g = r2 % 12;
        bf16x8 val;
        #pragma unroll
        for (int i = 0; i < 8; ++i) {
            const int n = g * 8 + i;
            const uint32 p = (n < NP) ? HL[n][row] : 0u;
            val[i] = (short)(sel ? (p & 0xffffu) : (p >> 16));
        }
        (sel ? weT_lo : weT_hi)[(b * HW2_ + kb + row) * 12 + g] = val;
    }
}

// ---------------------------------------------------------------------------
// Kernel 2: fused scores^T -> softmax -> out via MFMA (3-term split).
// Structure = round 7 (8 waves, K-eighth / kout-eighth, plain loads, TLP).
// NEW: feat loads + out stores NON-TEMPORAL (streaming 16 MB/XCD stops
// evicting the 2.8 MB/XCD we/weT set from L2; re-reads run at L2 rate).
// ---------------------------------------------------------------------------
__global__ __launch_bounds__(512, 4) void attn_mfma(
    const float* __restrict__ feat,
    const bf16x8* __restrict__ we_hi, const bf16x8* __restrict__ we_lo,
    const bf16x8* __restrict__ weT_hi, const bf16x8* __restrict__ weT_lo,
    float* __restrict__ out)
{
    __shared__ __align__(16) float S[8][16][84];  // partial scores (43 KB)
    __shared__ __align__(16) u16   Ph[32][NPT];   // P hi (6 KB)
    __shared__ __align__(16) u16   Pl[32][NPT];   // P lo (6 KB)

    const int id  = blockIdx.x;
    const int b   = (id & 7) + 8 * (id >> 7);     // batch -> XCD id&7 (=b%8)
    const int c0  = ((id >> 3) & 15) * 32;        // block's 32 c rows

    const int t    = threadIdx.x;
    const int h    = t >> 6;                      // wave = K-eighth, 0..7
    const int lane = t & 63, lr = lane & 15, lg = lane >> 4;

    const float* frow0 = feat + (size_t)(b * C_ + c0 + lr) * HW2_;
    const float* frow1 = frow0 + 16 * HW2_;

    // ---- Phase 1: scores^T[n][c], 2 strips, K-eighth per wave -------------
    f32x4 acc[2][5];
    #pragma unroll
    for (int s = 0; s < 2; ++s)
        #pragma unroll
        for (int m = 0; m < 5; ++m) acc[s][m] = (f32x4)0.0f;

    #pragma unroll
    for (int ks = 0; ks < 4; ++ks) {
        const int kk = h * 128 + ks * 32 + 8 * lg;
        bf16x8 fh0, fl0, fh1, fl1;
        {   f32x4 x = NTLOAD(frow0 + kk);
            f32x4 y = NTLOAD(frow0 + kk + 4);
            split8v(x, y, fh0, fl0); }
        {   f32x4 x = NTLOAD(frow1 + kk);
            f32x4 y = NTLOAD(frow1 + kk + 4);
            split8v(x, y, fh1, fl1); }
        const int qb  = (b * 16 + 2 * h + (ks >> 1)) * NP;
        const int sub = (ks & 1) * 4 + lg;
        #pragma unroll
        for (int m = 0; m < 5; ++m) {
            const int o = (qb + 16 * m + lr) * 8 + sub;
            const bf16x8 ah = we_hi[o];
            const bf16x8 al = we_lo[o];
            acc[0][m] = MFMA(ah, fh0, acc[0][m]);
            acc[0][m] = MFMA(ah, fl0, acc[0][m]);
            acc[0][m] = MFMA(al, fh0, acc[0][m]);
            acc[1][m] = MFMA(ah, fh1, acc[1][m]);
            acc[1][m] = MFMA(ah, fl1, acc[1][m]);
            acc[1][m] = MFMA(al, fh1, acc[1][m]);
        }
    }

    // ---- merge (8 partials) + softmax, one 16-row strip at a time ---------
    #pragma unroll
    for (int s = 0; s < 2; ++s) {
        #pragma unroll
        for (int m = 0; m < 5; ++m)
            #pragma unroll
            for (int r = 0; r < 4; ++r)
                S[h][lr][16 * m + 4 * lg + r] = acc[s][m][r];
        __syncthreads();
        {
            // wave h owns 2 rows: srow = 2h + (lane>>5); 32 lanes per row
            const int srow = 2 * h + (lane >> 5), col0 = lane & 31;
            float v3[3];
            float mx = -3.0e38f;
            #pragma unroll
            for (int j = 0; j < 3; ++j) {
                const int n = col0 + 32 * j;
                float sv = S[0][srow][n] + S[1][srow][n] + S[2][srow][n] + S[3][srow][n]
                         + S[4][srow][n] + S[5][srow][n] + S[6][srow][n] + S[7][srow][n];
                if (n < NW) mx = fmaxf(mx, sv);
                v3[j] = sv;
            }
            mx = fmaxf(mx, __shfl_xor(mx, 1));
            mx = fmaxf(mx, __shfl_xor(mx, 2));
            mx = fmaxf(mx, __shfl_xor(mx, 4));
            mx = fmaxf(mx, __shfl_xor(mx, 8));
            mx = fmaxf(mx, __shfl_xor(mx, 16));
            float sum = 0.f;
            #pragma unroll
            for (int j = 0; j < 3; ++j) {
                const int n = col0 + 32 * j;
                const float e = (n < NW) ? __expf(v3[j] - mx) : 0.f;
                v3[j] = e; sum += e;
            }
            sum += __shfl_xor(sum, 1);
            sum += __shfl_xor(sum, 2);
            sum += __shfl_xor(sum, 4);
            sum += __shfl_xor(sum, 8);
            sum += __shfl_xor(sum, 16);
            const float inv = 1.0f / sum;
            #pragma unroll
            for (int j = 0; j < 3; ++j) {
                const int n = col0 + 32 * j;
                u16 ph, pl; split1(v3[j] * inv, ph, pl);
                Ph[16 * s + srow][n] = ph; Pl[16 * s + srow][n] = pl;
            }
        }
        __syncthreads();
    }

    // ---- Phase 3: out^T[kout][c] = weT . P^T; wave h owns kout-eighth -----
    bf16x8 pbh[2][3], pbl[2][3];
    #pragma unroll
    for (int s = 0; s < 2; ++s)
        #pragma unroll
        for (int ksn = 0; ksn < 3; ++ksn) {
            pbh[s][ksn] = *(const bf16x8*)&Ph[16 * s + lr][32 * ksn + 8 * lg];
            pbl[s][ksn] = *(const bf16x8*)&Pl[16 * s + lr][32 * ksn + 8 * lg];
        }
    const bf16x8* th = weT_hi + (size_t)b * HW2_ * 12;
    const bf16x8* tl = weT_lo + (size_t)b * HW2_ * 12;
    float* orow0 = out + (size_t)(b * C_ + c0 + lr) * HW2_;
    float* orow1 = orow0 + 16 * HW2_;

    #pragma unroll
    for (int tt = 0; tt < 8; ++tt) {
        const int row = h * 128 + tt * 16 + lr;
        bf16x8 wa[3], wb[3];
        #pragma unroll
        for (int ksn = 0; ksn < 3; ++ksn) {
            wa[ksn] = th[row * 12 + 4 * ksn + lg];
            wb[ksn] = tl[row * 12 + 4 * ksn + lg];
        }
        f32x4 o0 = (f32x4)0.0f, o1 = (f32x4)0.0f;
        #pragma unroll
        for (int ksn = 0; ksn < 3; ++ksn) {
            o0 = MFMA(wa[ksn], pbh[0][ksn], o0);
            o0 = MFMA(wa[ksn], pbl[0][ksn], o0);
            o0 = MFMA(wb[ksn], pbh[0][ksn], o0);
            o1 = MFMA(wa[ksn], pbh[1][ksn], o1);
            o1 = MFMA(wa[ksn], pbl[1][ksn], o1);
            o1 = MFMA(wb[ksn], pbh[1][ksn], o1);
        }
        const int col = h * 128 + tt * 16 + 4 * lg;
        NTSTORE(o0, orow0 + col);
        NTSTORE(o1, orow1 + col);
    }
}

// ---------------------------------------------------------------------------
extern "C" void kernel_launch(void* const* d_in, const int* in_sizes, int n_in,
                              void* d_out, int out_size, void* d_ws, size_t ws_size,
                              hipStream_t stream) {
    (void)in_sizes; (void)n_in; (void)out_size; (void)ws_size;
    const float* feat     = (const float*)d_in[0];
    const float* word_emb = (const float*)d_in[1];
    const float* W_fc     = (const float*)d_in[2];
    const float* b_fc     = (const float*)d_in[3];

    bf16x8* we_hi  = (bf16x8*)d_ws;
    bf16x8* we_lo  = we_hi  + WE_ELN;
    bf16x8* weT_hi = we_lo  + WE_ELN;
    bf16x8* weT_lo = weT_hi + WET_ELN;

    we_gemm<<<512, 512, 0, stream>>>(word_emb, W_fc, b_fc, we_hi, we_lo, weT_hi, weT_lo);
    attn_mfma<<<512, 512, 0, stream>>>(feat, we_hi, we_lo, weT_hi, weT_lo, (float*)d_out);
}